// Round 12
// baseline (100.549 us; speedup 1.0000x reference)
//
#include <hip/hip_runtime.h>
#include <hip/hip_bf16.h>

#define EPSF 1e-5f

typedef __attribute__((ext_vector_type(8))) short bf16x8;
typedef __attribute__((ext_vector_type(4))) float f32x4;
typedef __attribute__((ext_vector_type(4))) unsigned int u32x4;

__device__ __forceinline__ unsigned short f2bf(float f) {
  union { float f; unsigned u; } v; v.f = f;
  unsigned r = v.u + 0x7fffu + ((v.u >> 16) & 1u);
  return (unsigned short)(r >> 16);
}

// 8 fp32 -> 8 bf16 (RNE) via packed HW cvt.
__device__ __forceinline__ u32x4 cvtpk8(f32x4 a, f32x4 b) {
  u32x4 r;
  asm("v_cvt_pk_bf16_f32 %0, %1, %2" : "=v"(r[0]) : "v"(a[0]), "v"(a[1]));
  asm("v_cvt_pk_bf16_f32 %0, %1, %2" : "=v"(r[1]) : "v"(a[2]), "v"(a[3]));
  asm("v_cvt_pk_bf16_f32 %0, %1, %2" : "=v"(r[2]) : "v"(b[0]), "v"(b[1]));
  asm("v_cvt_pk_bf16_f32 %0, %1, %2" : "=v"(r[3]) : "v"(b[2]), "v"(b[3]));
  return r;
}

// ---------------- prep: fold BN, cast bf16, PACK w1 fragment-major ----------------
// Packed chunk (16B) index: (((m*4 + c)*64 + kt)*8 + f)*64 + l
//   f = st*4 + j;  col n = c*64 + j*16 + (l&15);  k = kt*64 + st*32 + (l>>4)*8 .. +8
__global__ void prep_kernel(const float* __restrict__ w1, const float* __restrict__ b1,
                            const float* __restrict__ g1, const float* __restrict__ be1,
                            const float* __restrict__ m1, const float* __restrict__ v1,
                            const float* __restrict__ w2, const float* __restrict__ b2,
                            const float* __restrict__ g2, const float* __restrict__ be2,
                            const float* __restrict__ m2, const float* __restrict__ v2,
                            unsigned short* __restrict__ w1p, unsigned short* __restrict__ w2f,
                            float* __restrict__ bias1, float* __restrict__ bias2) {
  int idx = blockIdx.x * blockDim.x + threadIdx.x;
  int stride = gridDim.x * blockDim.x;
  for (int i = idx; i < 262144; i += stride) {     // 2*4*64*8*64 chunks
    int l  = i & 63;
    int f  = (i >> 6) & 7;
    int kt = (i >> 9) & 63;
    int c  = (i >> 15) & 3;
    int m  = i >> 17;
    int st = f >> 2, j = f & 3;
    int n  = c * 64 + j * 16 + (l & 15);
    int k0 = kt * 64 + st * 32 + (l >> 4) * 8;
    int mn = m * 256 + n;
    float inv = g1[mn] * rsqrtf(v1[mn] + EPSF);
    const float* src = w1 + (size_t)mn * 4096 + k0;
    unsigned short* dst = w1p + (size_t)i * 8;
#pragma unroll
    for (int e = 0; e < 8; ++e) dst[e] = f2bf(src[e] * inv);
  }
  for (int i = idx; i < 2 * 128 * 256; i += stride) {
    int mj = i >> 8;
    float inv = g2[mj] * rsqrtf(v2[mj] + EPSF);
    w2f[i] = f2bf(w2[i] * inv);
  }
  if (idx < 512) {
    float inv = g1[idx] * rsqrtf(v1[idx] + EPSF);
    bias1[idx] = b1[idx] * inv + be1[idx] - m1[idx] * inv;
  }
  if (idx < 256) {
    float inv = g2[idx] * rsqrtf(v2[idx] + EPSF);
    bias2[idx] = b2[idx] * inv + be2[idx] - m2[idx] * inv;
  }
}

// ---- step-body macros (R7-proven): named arrays, constant-indexed ----
#define BLOAD(BN, KT)                                                  \
  {                                                                    \
    BN[0] = *(const bf16x8*)(pB + (size_t)(KT) * 8192 + 0 * 1024);     \
    BN[1] = *(const bf16x8*)(pB + (size_t)(KT) * 8192 + 1 * 1024);     \
    BN[2] = *(const bf16x8*)(pB + (size_t)(KT) * 8192 + 2 * 1024);     \
    BN[3] = *(const bf16x8*)(pB + (size_t)(KT) * 8192 + 3 * 1024);     \
    BN[4] = *(const bf16x8*)(pB + (size_t)(KT) * 8192 + 4 * 1024);     \
    BN[5] = *(const bf16x8*)(pB + (size_t)(KT) * 8192 + 5 * 1024);     \
    BN[6] = *(const bf16x8*)(pB + (size_t)(KT) * 8192 + 6 * 1024);     \
    BN[7] = *(const bf16x8*)(pB + (size_t)(KT) * 8192 + 7 * 1024);     \
  }

#define ALOAD(AR, KOFF)                                                \
  {                                                                    \
    AR[0] = *(const f32x4*)(aSrc + (KOFF));                            \
    AR[1] = *(const f32x4*)(aSrc + (KOFF) + 4);                        \
    AR[2] = *(const f32x4*)(aSrc + (KOFF) + 8);                        \
    AR[3] = *(const f32x4*)(aSrc + (KOFF) + 12);                       \
  }

#define AWRITE(AR, DBASE)                                              \
  {                                                                    \
    u32x4 lo_ = cvtpk8(AR[0], AR[1]);                                  \
    u32x4 hi_ = cvtpk8(AR[2], AR[3]);                                  \
    *(u32x4*)((DBASE) + aOff0) = lo_;                                  \
    *(u32x4*)((DBASE) + aOff1) = hi_;                                  \
  }

#define AFREAD(ABUF)                                                   \
  {                                                                    \
    _Pragma("unroll") for (int st = 0; st < 2; ++st)                   \
    _Pragma("unroll") for (int i = 0; i < 4; ++i) {                    \
      int row_ = i * 16 + l15;                                         \
      int g_ = st * 4 + lq;                                            \
      aF[st][i] = *(const bf16x8*)((ABUF) + row_ * 128 + ((g_ ^ (row_ & 7)) << 4)); \
    }                                                                  \
  }

#define MFMA16(BC)                                                     \
  {                                                                    \
    _Pragma("unroll") for (int st = 0; st < 2; ++st)                   \
    _Pragma("unroll") for (int i = 0; i < 4; ++i)                      \
    _Pragma("unroll") for (int j = 0; j < 4; ++j)                      \
      acc[i][j] = __builtin_amdgcn_mfma_f32_16x16x32_bf16(aF[st][i], BC[st * 4 + j], acc[i][j], 0, 0, 0); \
  }

#define BOUNDARY()                                                     \
  __builtin_amdgcn_sched_barrier(0x77);                                \
  asm volatile("s_waitcnt lgkmcnt(0)");                                \
  __builtin_amdgcn_s_barrier();                                        \
  __builtin_amdgcn_sched_barrier(0x77);

// ---------------- kernel 1: layer-1 GEMM, split-K=2 ----------------
// 512 blocks (2/CU with DIFFERENT K-halves -> decorrelated phases), 256 threads.
// Block: kh (K-half, 2048), mdl, rb (64 rows); wave wv owns cols wv*64..+63.
// Writes raw fp32 partial acc to X1p[kh] (no bias/relu here).
__global__ __launch_bounds__(256) void gemm1_kernel(
    const float* __restrict__ h,
    const unsigned short* __restrict__ w1p,
    float* __restrict__ X1p) {
  __shared__ __align__(16) char lds[16384];   // A'[2] @ 0/8192, 64x64 bf16 swizzled

  const int tid = threadIdx.x;
  const int lane = tid & 63;
  const int wv = tid >> 6;
  const int l15 = lane & 15;
  const int lq = lane >> 4;

  const int bid = blockIdx.x;
  const int kh = bid >> 8;                        // 0..1 K-half
  const int b8 = bid & 255;
  const int mdl = (b8 >> 2) & 1;                  // model per XCD-half
  const int rb = (b8 >> 3) * 4 + (b8 & 3);        // 0..127 per model

  const float* hM = h + ((size_t)mdl * 8192 + (size_t)rb * 64) * 4096 + kh * 2048;
  // packed B base: wave's col-block + this K-half (32 kt x 8192 B)
  const char* pB = (const char*)w1p + (size_t)(mdl * 4 + wv) * 524288
                   + (size_t)kh * 262144 + lane * 16;

  // A staging: thread t -> row = t>>2 (0..63), kseg = t&3 (16 fp32 each)
  const int arow = tid >> 2;
  const int akseg = tid & 3;
  const float* aSrc = hM + (size_t)arow * 4096 + akseg * 16;
  const int ax = arow & 7;
  const int aOff0 = arow * 128 + (((akseg * 2) ^ ax) << 4);
  const int aOff1 = arow * 128 + (((akseg * 2 + 1) ^ ax) << 4);

  f32x4 acc[4][4];
#pragma unroll
  for (int i = 0; i < 4; ++i)
#pragma unroll
    for (int j = 0; j < 4; ++j)
#pragma unroll
      for (int q = 0; q < 4; ++q) acc[i][j][q] = 0.f;

  bf16x8 bb0[8], bb1[8];
  f32x4 aR0[4], aR1[4];
  bf16x8 aF[2][4];

  char* const Ab0 = lds;
  char* const Ab1 = lds + 8192;

  // ---- prologue ----
  ALOAD(aR0, 0)
  BLOAD(bb0, 0)
  ALOAD(aR1, 64)
  AWRITE(aR0, Ab0)
  BOUNDARY()

#pragma unroll 1
  for (int kt2 = 0; kt2 < 15; ++kt2) {
    const int kt = kt2 * 2;
    AFREAD(Ab0)
    BLOAD(bb1, kt + 1)
    ALOAD(aR0, (kt + 2) * 64)
    MFMA16(bb0)
    AWRITE(aR1, Ab1)
    BOUNDARY()
    AFREAD(Ab1)
    BLOAD(bb0, kt + 2)
    ALOAD(aR1, (kt + 3) * 64)
    MFMA16(bb1)
    AWRITE(aR0, Ab0)
    BOUNDARY()
  }
  // kt=30: prefetch B(31); write data31 (aR1) -> Ab1; no A-global load
  AFREAD(Ab0)
  BLOAD(bb1, 31)
  MFMA16(bb0)
  AWRITE(aR1, Ab1)
  BOUNDARY()
  // kt=31: compute only
  AFREAD(Ab1)
  MFMA16(bb1)

  // ---- epilogue: store raw fp32 partials, coalesced per 16-lane group ----
  float* Xb = X1p + ((size_t)kh * 16384 + (size_t)mdl * 8192 + (size_t)rb * 64) * 256;
#pragma unroll
  for (int i = 0; i < 4; ++i) {
#pragma unroll
    for (int j = 0; j < 4; ++j) {
      int n = wv * 64 + j * 16 + l15;
#pragma unroll
      for (int q = 0; q < 4; ++q) {
        int row = i * 16 + lq * 4 + q;
        Xb[(size_t)row * 256 + n] = acc[i][j][q];
      }
    }
  }
}

// ---------------- kernel 2: sum partials + BN/ReLU + layers 2-3 ----------------
// 256 blocks, 256 threads (4 waves). Block: mdl, rb (64 rows).
__global__ __launch_bounds__(256) void heads_kernel(
    const float* __restrict__ X1p,
    const unsigned short* __restrict__ w2f,
    const float* __restrict__ bias1,
    const float* __restrict__ bias2,
    const float* __restrict__ w3,
    const float* __restrict__ b3,
    float* __restrict__ out) {
  // X1 @ 0 (64x256 bf16 swizzled, 32KB), part @ 32768 (4x64 fp32)
  __shared__ __align__(16) char lds[33792];

  const int tid = threadIdx.x;
  const int lane = tid & 63;
  const int wv = tid >> 6;
  const int l15 = lane & 15;
  const int lq = lane >> 4;

  const int bid = blockIdx.x;
  const int mdl = (bid >> 2) & 1;
  const int rb = (bid >> 3) * 4 + (bid & 3);      // 0..127

  // ---- sum partials + bias + relu -> X1 bf16 LDS (swizzled) ----
  // thread t: row r = t>>2 (0..63), seg = t&3 (cols seg*64..+63)
  {
    const int r = tid >> 2;
    const int seg = tid & 3;
    const float* xp0 = X1p + ((size_t)mdl * 8192 + (size_t)rb * 64 + r) * 256 + seg * 64;
    const float* xp1 = xp0 + (size_t)16384 * 256;
    const float* bs = bias1 + mdl * 256 + seg * 64;
#pragma unroll
    for (int g = 0; g < 8; ++g) {
      f32x4 a0 = *(const f32x4*)(xp0 + g * 8);
      f32x4 a1 = *(const f32x4*)(xp0 + g * 8 + 4);
      f32x4 c0 = *(const f32x4*)(xp1 + g * 8);
      f32x4 c1 = *(const f32x4*)(xp1 + g * 8 + 4);
      f32x4 d0 = *(const f32x4*)(bs + g * 8);
      f32x4 d1 = *(const f32x4*)(bs + g * 8 + 4);
#pragma unroll
      for (int e = 0; e < 4; ++e) {
        a0[e] = fmaxf(a0[e] + c0[e] + d0[e], 0.f);
        a1[e] = fmaxf(a1[e] + c1[e] + d1[e], 0.f);
      }
      u32x4 w = cvtpk8(a0, a1);
      int gran = seg * 8 + g;                   // 16B granule (8 cols)
      *(u32x4*)(lds + r * 512 + ((gran ^ (r & 7)) << 4)) = w;
    }
  }
  __syncthreads();

  // ---- layer2: 64x128, K=256 over X1; w2 frags direct from L2 ----
  f32x4 acc2[4][2];
#pragma unroll
  for (int i = 0; i < 4; ++i)
#pragma unroll
    for (int j = 0; j < 2; ++j)
#pragma unroll
      for (int q = 0; q < 4; ++q) acc2[i][j][q] = 0.f;

  const unsigned short* w2m = w2f + mdl * (128 * 256);
#pragma unroll
  for (int st = 0; st < 8; ++st) {
    int k8 = st * 32 + lq * 8;
    bf16x8 aX[4], bW[2];
#pragma unroll
    for (int i = 0; i < 4; ++i) {
      int row = i * 16 + l15;
      aX[i] = *(const bf16x8*)(lds + row * 512 + ((((k8 >> 3) ^ (row & 7)) << 4)));
    }
#pragma unroll
    for (int j = 0; j < 2; ++j) {
      int n2 = wv * 32 + j * 16 + l15;
      bW[j] = *(const bf16x8*)(w2m + n2 * 256 + k8);
    }
#pragma unroll
    for (int i = 0; i < 4; ++i)
#pragma unroll
      for (int j = 0; j < 2; ++j)
        acc2[i][j] = __builtin_amdgcn_mfma_f32_16x16x32_bf16(aX[i], bW[j], acc2[i][j], 0, 0, 0);
  }

  // ---- layer3: relu(x2)*w3 dot, 16-lane reduce, cross-wave reduce ----
  float w3v[2], b2v[2];
#pragma unroll
  for (int j = 0; j < 2; ++j) {
    int n2 = wv * 32 + j * 16 + l15;
    w3v[j] = w3[mdl * 128 + n2];
    b2v[j] = bias2[mdl * 128 + n2];
  }
  float* part = (float*)(lds + 32768);   // [4][64]
#pragma unroll
  for (int i = 0; i < 4; ++i) {
#pragma unroll
    for (int q = 0; q < 4; ++q) {
      float val = 0.f;
#pragma unroll
      for (int j = 0; j < 2; ++j) {
        float x = fmaxf(acc2[i][j][q] + b2v[j], 0.f);
        val += x * w3v[j];
      }
#pragma unroll
      for (int mk = 1; mk < 16; mk <<= 1) val += __shfl_xor(val, mk, 64);
      if (l15 == 0) part[wv * 64 + i * 16 + lq * 4 + q] = val;
    }
  }
  __syncthreads();
  if (tid < 64) {
    float s = part[tid] + part[64 + tid] + part[128 + tid] + part[192 + tid] + b3[mdl];
    out[((size_t)(rb * 64 + tid)) * 2 + mdl] = s;
  }
}

extern "C" void kernel_launch(void* const* d_in, const int* in_sizes, int n_in,
                              void* d_out, int out_size, void* d_ws, size_t ws_size,
                              hipStream_t stream) {
  const float* h   = (const float*)d_in[0];
  const float* w1  = (const float*)d_in[1];
  const float* b1  = (const float*)d_in[2];
  const float* g1  = (const float*)d_in[3];
  const float* be1 = (const float*)d_in[4];
  const float* m1  = (const float*)d_in[5];
  const float* v1  = (const float*)d_in[6];
  const float* w2  = (const float*)d_in[7];
  const float* b2  = (const float*)d_in[8];
  const float* g2  = (const float*)d_in[9];
  const float* be2 = (const float*)d_in[10];
  const float* m2  = (const float*)d_in[11];
  const float* v2  = (const float*)d_in[12];
  const float* w3  = (const float*)d_in[13];
  const float* b3  = (const float*)d_in[14];

  char* ws = (char*)d_ws;
  unsigned short* w1p = (unsigned short*)ws;               // 4 MiB packed
  unsigned short* w2f = (unsigned short*)(ws + 4194304);   // 128 KiB
  float* bias1 = (float*)(ws + 4325376);
  float* bias2 = (float*)(ws + 4327424);
  float* X1p   = (float*)(ws + 8388608);                   // 2 x 16384 x 256 fp32 = 32 MiB

  prep_kernel<<<1024, 256, 0, stream>>>(w1, b1, g1, be1, m1, v1,
                                        w2, b2, g2, be2, m2, v2,
                                        w1p, w2f, bias1, bias2);
  gemm1_kernel<<<512, 256, 0, stream>>>(h, w1p, X1p);
  heads_kernel<<<256, 256, 0, stream>>>(X1p, w2f, bias1, bias2, w3, b3,
                                        (float*)d_out);
}

// Round 13
// 71.315 us; speedup vs baseline: 1.4099x; 1.4099x over previous
//
#include <hip/hip_runtime.h>
#include <hip/hip_bf16.h>

#define EPSF 1e-5f

typedef __attribute__((ext_vector_type(8))) short bf16x8;
typedef __attribute__((ext_vector_type(4))) float f32x4;
typedef __attribute__((ext_vector_type(4))) unsigned int u32x4;

__device__ __forceinline__ unsigned short f2bf(float f) {
  union { float f; unsigned u; } v; v.f = f;
  unsigned r = v.u + 0x7fffu + ((v.u >> 16) & 1u);
  return (unsigned short)(r >> 16);
}

// 8 fp32 -> 8 bf16 (RNE) via packed HW cvt.
__device__ __forceinline__ u32x4 cvtpk8(f32x4 a, f32x4 b) {
  u32x4 r;
  asm("v_cvt_pk_bf16_f32 %0, %1, %2" : "=v"(r[0]) : "v"(a[0]), "v"(a[1]));
  asm("v_cvt_pk_bf16_f32 %0, %1, %2" : "=v"(r[1]) : "v"(a[2]), "v"(a[3]));
  asm("v_cvt_pk_bf16_f32 %0, %1, %2" : "=v"(r[2]) : "v"(b[0]), "v"(b[1]));
  asm("v_cvt_pk_bf16_f32 %0, %1, %2" : "=v"(r[3]) : "v"(b[2]), "v"(b[3]));
  return r;
}

// ---------------- prep: fold BN, cast bf16, PACK w1 fragment-major ----------------
// Packed chunk (16B) index: (((m*4 + c)*64 + kt)*8 + f)*64 + l
//   f = st*4 + j;  col n = c*64 + j*16 + (l&15);  k = kt*64 + st*32 + (l>>4)*8 .. +8
__global__ void prep_kernel(const float* __restrict__ w1, const float* __restrict__ b1,
                            const float* __restrict__ g1, const float* __restrict__ be1,
                            const float* __restrict__ m1, const float* __restrict__ v1,
                            const float* __restrict__ w2, const float* __restrict__ b2,
                            const float* __restrict__ g2, const float* __restrict__ be2,
                            const float* __restrict__ m2, const float* __restrict__ v2,
                            unsigned short* __restrict__ w1p, unsigned short* __restrict__ w2f,
                            float* __restrict__ bias1, float* __restrict__ bias2) {
  int idx = blockIdx.x * blockDim.x + threadIdx.x;
  int stride = gridDim.x * blockDim.x;
  for (int i = idx; i < 262144; i += stride) {     // 2*4*64*8*64 chunks
    int l  = i & 63;
    int f  = (i >> 6) & 7;
    int kt = (i >> 9) & 63;
    int c  = (i >> 15) & 3;
    int m  = i >> 17;
    int st = f >> 2, j = f & 3;
    int n  = c * 64 + j * 16 + (l & 15);
    int k0 = kt * 64 + st * 32 + (l >> 4) * 8;
    int mn = m * 256 + n;
    float inv = g1[mn] * rsqrtf(v1[mn] + EPSF);
    const float* src = w1 + (size_t)mn * 4096 + k0;
    unsigned short* dst = w1p + (size_t)i * 8;
#pragma unroll
    for (int e = 0; e < 8; ++e) dst[e] = f2bf(src[e] * inv);
  }
  for (int i = idx; i < 2 * 128 * 256; i += stride) {
    int mj = i >> 8;
    float inv = g2[mj] * rsqrtf(v2[mj] + EPSF);
    w2f[i] = f2bf(w2[i] * inv);
  }
  if (idx < 512) {
    float inv = g1[idx] * rsqrtf(v1[idx] + EPSF);
    bias1[idx] = b1[idx] * inv + be1[idx] - m1[idx] * inv;
  }
  if (idx < 256) {
    float inv = g2[idx] * rsqrtf(v2[idx] + EPSF);
    bias2[idx] = b2[idx] * inv + be2[idx] - m2[idx] * inv;
  }
}

// ---- step-body macros: top-level named arrays, constant-indexed ----
// Per wave per step: 4 coalesced B loads (64 lanes x consecutive 16B each).
#define BLOAD(BN, KT)                                                  \
  {                                                                    \
    BN[0] = *(const bf16x8*)(pB + (size_t)(KT) * 8192 + 0);            \
    BN[1] = *(const bf16x8*)(pB + (size_t)(KT) * 8192 + 1024);         \
    BN[2] = *(const bf16x8*)(pB + (size_t)(KT) * 8192 + 4096);         \
    BN[3] = *(const bf16x8*)(pB + (size_t)(KT) * 8192 + 5120);         \
  }

#define ALOAD(AR, KOFF)                                                \
  {                                                                    \
    AR[0] = *(const f32x4*)(aSrc + (KOFF));                            \
    AR[1] = *(const f32x4*)(aSrc + (KOFF) + 4);                        \
  }

#define AWRITE(AR, DBASE)                                              \
  {                                                                    \
    u32x4 w_ = cvtpk8(AR[0], AR[1]);                                   \
    *(u32x4*)((DBASE) + aOff) = w_;                                    \
  }

#define AFREAD(ABUF)                                                   \
  {                                                                    \
    _Pragma("unroll") for (int st = 0; st < 2; ++st)                   \
    _Pragma("unroll") for (int i = 0; i < 4; ++i) {                    \
      int row_ = i * 16 + l15;                                         \
      int g_ = st * 4 + lq;                                            \
      aF[st][i] = *(const bf16x8*)((ABUF) + row_ * 128 + ((g_ ^ (row_ & 7)) << 4)); \
    }                                                                  \
  }

#define MFMA8(BC)                                                      \
  {                                                                    \
    _Pragma("unroll") for (int st = 0; st < 2; ++st)                   \
    _Pragma("unroll") for (int i = 0; i < 4; ++i)                      \
    _Pragma("unroll") for (int j = 0; j < 2; ++j)                      \
      acc[i][j] = __builtin_amdgcn_mfma_f32_16x16x32_bf16(aF[st][i], BC[st * 2 + j], acc[i][j], 0, 0, 0); \
  }

// DS + MFMA pinned; ALU + VMEM may cross. lgkmcnt(0) orders ds ops before barrier.
#define BOUNDARY()                                                     \
  __builtin_amdgcn_sched_barrier(0x77);                                \
  asm volatile("s_waitcnt lgkmcnt(0)");                                \
  __builtin_amdgcn_s_barrier();                                        \
  __builtin_amdgcn_sched_barrier(0x77);

// ---------------- fused heads kernel ----------------
// 256 blocks (1/CU), 512 threads = 8 waves (2/SIMD); wave wv owns layer1 cols wv*32..
// Same per-CU traffic as the 4-wave version (N split 8 ways, no duplication):
// B: packed fragment-major global->reg dbuf (counted vmcnt). A: reg->cvt_pk->LDS dbuf.
__global__ __launch_bounds__(512) void fused_heads_kernel(
    const float* __restrict__ h,
    const unsigned short* __restrict__ w1p,
    const unsigned short* __restrict__ w2f,
    const float* __restrict__ bias1,
    const float* __restrict__ bias2,
    const float* __restrict__ w3,
    const float* __restrict__ b3,
    float* __restrict__ out) {
  // loop: A'[2] @ 0/8192 (64x64 bf16, granule-swizzled)
  // epilogue: X1 @ 0 (64x256 bf16 swizzled, 32KB), part @ 32768 (8x64 fp32)
  __shared__ __align__(16) char lds[34816];

  const int tid = threadIdx.x;
  const int lane = tid & 63;
  const int wv = tid >> 6;        // 0..7, owns layer1 cols wv*32..+31
  const int l15 = lane & 15;
  const int lq = lane >> 4;

  const int bid = blockIdx.x;
  const int mdl = (bid >> 2) & 1;                 // model per XCD-half
  const int rb = (bid >> 3) * 4 + (bid & 3);      // 0..127 per model

  const float* hM = h + ((size_t)mdl * 8192 + (size_t)rb * 64) * 4096;
  // packed B base: col-block c = wv>>1; fold (wv&1)*2 frag offset + lane*16 in.
  const char* pB = (const char*)w1p + (size_t)(mdl * 4 + (wv >> 1)) * 524288
                   + (wv & 1) * 2048 + lane * 16;

  // A staging: thread t -> row = t>>3 (0..63), kseg = t&7 (8 fp32 each)
  const int arow = tid >> 3;
  const int akseg = tid & 7;
  const float* aSrc = hM + (size_t)arow * 4096 + akseg * 8;
  const int aOff = arow * 128 + ((akseg ^ (arow & 7)) << 4);

  f32x4 acc[4][2];
#pragma unroll
  for (int i = 0; i < 4; ++i)
#pragma unroll
    for (int j = 0; j < 2; ++j)
#pragma unroll
      for (int q = 0; q < 4; ++q) acc[i][j][q] = 0.f;

  bf16x8 bb0[4], bb1[4];   // B frags [st*2+j], parity-rotated
  f32x4 aR0[2], aR1[2];    // A stage regs, parity-rotated
  bf16x8 aF[2][4];         // A fragments (transient per step)

  char* const Ab0 = lds;
  char* const Ab1 = lds + 8192;

  // ---- prologue ----
  ALOAD(aR0, 0)
  BLOAD(bb0, 0)
  ALOAD(aR1, 64)
  AWRITE(aR0, Ab0)
  BOUNDARY()

#pragma unroll 1
  for (int kt2 = 0; kt2 < 31; ++kt2) {
    const int kt = kt2 * 2;
    // even step kt: cur=Ab0/bb0; prefetch B(kt+1)->bb1, A(kt+2)->aR0; cvt aR1->Ab1
    AFREAD(Ab0)
    BLOAD(bb1, kt + 1)
    ALOAD(aR0, (kt + 2) * 64)
    MFMA8(bb0)
    AWRITE(aR1, Ab1)
    BOUNDARY()
    // odd step kt+1: cur=Ab1/bb1; prefetch B(kt+2)->bb0, A(kt+3)->aR1; cvt aR0->Ab0
    AFREAD(Ab1)
    BLOAD(bb0, kt + 2)
    ALOAD(aR1, (kt + 3) * 64)
    MFMA8(bb1)
    AWRITE(aR0, Ab0)
    BOUNDARY()
  }
  // kt=62: cur=Ab0/bb0; prefetch B(63)->bb1; cvt aR1(=data63)->Ab1
  AFREAD(Ab0)
  BLOAD(bb1, 63)
  MFMA8(bb0)
  AWRITE(aR1, Ab1)
  BOUNDARY()
  // kt=63: cur=Ab1/bb1; boundary protects epilogue LDS reuse
  AFREAD(Ab1)
  MFMA8(bb1)
  BOUNDARY()

  // ---- epilogue layer1: bias + relu -> X1 bf16 in LDS (swizzled) ----
  float b1v[2];
#pragma unroll
  for (int j = 0; j < 2; ++j) b1v[j] = bias1[mdl * 256 + wv * 32 + j * 16 + l15];
#pragma unroll
  for (int i = 0; i < 4; ++i) {
#pragma unroll
    for (int j = 0; j < 2; ++j) {
      int n = wv * 32 + j * 16 + l15;
#pragma unroll
      for (int q = 0; q < 4; ++q) {
        int row = i * 16 + lq * 4 + q;       // C layout: col=l15, row=lq*4+q
        float x = fmaxf(acc[i][j][q] + b1v[j], 0.f);
        *(unsigned short*)(lds + row * 512 + ((((n >> 3) ^ (row & 7)) << 4) | ((n & 7) << 1))) = f2bf(x);
      }
    }
  }
  __syncthreads();

  // ---- layer2: 64 rows x 16 cols per wave, K=256 over X1; w2 direct from L2 ----
  f32x4 acc2[4];
#pragma unroll
  for (int i = 0; i < 4; ++i)
#pragma unroll
    for (int q = 0; q < 4; ++q) acc2[i][q] = 0.f;

  const unsigned short* w2m = w2f + mdl * (128 * 256);
#pragma unroll
  for (int st = 0; st < 8; ++st) {
    int k8 = st * 32 + lq * 8;
    bf16x8 aX[4], bW;
#pragma unroll
    for (int i = 0; i < 4; ++i) {
      int row = i * 16 + l15;
      aX[i] = *(const bf16x8*)(lds + row * 512 + ((((k8 >> 3) ^ (row & 7)) << 4)));
    }
    {
      int n2 = wv * 16 + l15;
      bW = *(const bf16x8*)(w2m + n2 * 256 + k8);
    }
#pragma unroll
    for (int i = 0; i < 4; ++i)
      acc2[i] = __builtin_amdgcn_mfma_f32_16x16x32_bf16(aX[i], bW, acc2[i], 0, 0, 0);
  }

  // ---- layer3: relu(x2)*w3 dot, 16-lane reduce, cross-wave reduce ----
  float w3v, b2v;
  {
    int n2 = wv * 16 + l15;
    w3v = w3[mdl * 128 + n2];
    b2v = bias2[mdl * 128 + n2];
  }
  float* part = (float*)(lds + 32768);   // [8][64]
#pragma unroll
  for (int i = 0; i < 4; ++i) {
#pragma unroll
    for (int q = 0; q < 4; ++q) {
      float x = fmaxf(acc2[i][q] + b2v, 0.f);
      float val = x * w3v;
#pragma unroll
      for (int mk = 1; mk < 16; mk <<= 1) val += __shfl_xor(val, mk, 64);
      if (l15 == 0) part[wv * 64 + i * 16 + lq * 4 + q] = val;
    }
  }
  __syncthreads();
  if (tid < 64) {
    float s = part[tid] + part[64 + tid] + part[128 + tid] + part[192 + tid]
            + part[256 + tid] + part[320 + tid] + part[384 + tid] + part[448 + tid]
            + b3[mdl];
    out[((size_t)(rb * 64 + tid)) * 2 + mdl] = s;
  }
}

extern "C" void kernel_launch(void* const* d_in, const int* in_sizes, int n_in,
                              void* d_out, int out_size, void* d_ws, size_t ws_size,
                              hipStream_t stream) {
  const float* h   = (const float*)d_in[0];
  const float* w1  = (const float*)d_in[1];
  const float* b1  = (const float*)d_in[2];
  const float* g1  = (const float*)d_in[3];
  const float* be1 = (const float*)d_in[4];
  const float* m1  = (const float*)d_in[5];
  const float* v1  = (const float*)d_in[6];
  const float* w2  = (const float*)d_in[7];
  const float* b2  = (const float*)d_in[8];
  const float* g2  = (const float*)d_in[9];
  const float* be2 = (const float*)d_in[10];
  const float* m2  = (const float*)d_in[11];
  const float* v2  = (const float*)d_in[12];
  const float* w3  = (const float*)d_in[13];
  const float* b3  = (const float*)d_in[14];

  char* ws = (char*)d_ws;
  unsigned short* w1p = (unsigned short*)ws;               // 4 MiB packed
  unsigned short* w2f = (unsigned short*)(ws + 4194304);   // 128 KiB
  float* bias1 = (float*)(ws + 4325376);
  float* bias2 = (float*)(ws + 4327424);

  prep_kernel<<<1024, 256, 0, stream>>>(w1, b1, g1, be1, m1, v1,
                                        w2, b2, g2, be2, m2, v2,
                                        w1p, w2f, bias1, bias2);
  fused_heads_kernel<<<256, 512, 0, stream>>>(h, w1p, w2f, bias1, bias2, w3, b3,
                                              (float*)d_out);
}